// Round 7
// baseline (655.147 us; speedup 1.0000x reference)
//
#include <hip/hip_runtime.h>
#include <hip/hip_bf16.h>

typedef unsigned short u16;
typedef unsigned int   u32;
typedef long long      i64;
typedef __attribute__((ext_vector_type(8))) short short8;  // 8 bf16 raw
typedef __attribute__((ext_vector_type(4))) float f32x4;

#define HD 128   // hidden / input feature dim
#define OUTD 64  // final output dim

__device__ __forceinline__ float bf2f(u16 u){ union{u32 i; float f;} x; x.i=((u32)u)<<16; return x.f; }
__device__ __forceinline__ u16 f2bf(float f){ __hip_bfloat16 h=__float2bfloat16(f); return *reinterpret_cast<u16*>(&h); }

// 8-element bf16 fragment loader: fp32 source converts, bf16 source is direct.
__device__ __forceinline__ short8 load8(const float* p){
  f32x4 lo = *reinterpret_cast<const f32x4*>(p);
  f32x4 hi = *reinterpret_cast<const f32x4*>(p + 4);
  short8 r;
  #pragma unroll
  for (int j=0;j<4;j++){ r[j]=(short)f2bf(lo[j]); r[4+j]=(short)f2bf(hi[j]); }
  return r;
}
__device__ __forceinline__ short8 load8(const u16* p){
  return *reinterpret_cast<const short8*>(p);
}

// index fetch that handles int32-vs-int64 delivery (flag: 1 = int32, 0 = int64)
__device__ __forceinline__ int idx_at(const void* p, int i, int is32){
  return is32 ? ((const int*)p)[i] : (int)((const i64*)p)[i];
}

// ---- dtype detect: int64 buffers of nonneg values have all odd words == 0 --
__global__ void k_detect(const u32* __restrict__ w, int* __restrict__ flag, int npairs){
  int i = blockIdx.x*256 + threadIdx.x;
  if (i < npairs && w[2*i+1] != 0) atomicOr(flag, 1);   // nonzero odd word -> int32
}

// ---- zero-fill output (ws-too-small fallback signal) ----------------------
__global__ void k_zero_out(float* __restrict__ out, int n){
  int i = blockIdx.x*256 + threadIdx.x;
  if (i < n) out[i] = 0.f;
}

// ---- CSR build ------------------------------------------------------------
__global__ void k_count(const void* __restrict__ ei, const int* __restrict__ flag,
                        int* __restrict__ cnt, int E){
  int e = blockIdx.x*256 + threadIdx.x;
  if (e < E){
    int d = idx_at(ei, E + e, *flag);   // dst = row 1
    atomicAdd(&cnt[d], 1);
  }
}

__global__ void k_chunk_sums(const int* __restrict__ cnt, int* __restrict__ csum, int n){
  __shared__ int sd[256];
  int c=blockIdx.x, t=threadIdx.x;
  int base=c*1024+t*4, s=0;
  #pragma unroll
  for (int k=0;k<4;k++){ int i=base+k; if(i<n) s+=cnt[i]; }
  sd[t]=s; __syncthreads();
  for (int o=128;o>0;o>>=1){ if(t<o) sd[t]+=sd[t+o]; __syncthreads(); }
  if (t==0) csum[c]=sd[0];
}

__global__ void k_scan_serial(int* csum, int m){
  if (threadIdx.x==0 && blockIdx.x==0){
    int acc=0;
    for (int i=0;i<m;i++){ int v=csum[i]; csum[i]=acc; acc+=v; }
  }
}

__global__ void k_scan_chunks(const int* __restrict__ cnt, const int* __restrict__ csum,
                              int* __restrict__ row_ptr, int* __restrict__ cursor,
                              float* __restrict__ dinv, int n, int total){
  __shared__ int sd[256];
  int c=blockIdx.x, t=threadIdx.x;
  int base=c*1024+t*4;
  int v[4], s=0;
  #pragma unroll
  for (int k=0;k<4;k++){ int i=base+k; v[k]=(i<n)?cnt[i]:0; s+=v[k]; }
  sd[t]=s; __syncthreads();
  for (int o=1;o<256;o<<=1){ int x=(t>=o)?sd[t-o]:0; __syncthreads(); sd[t]+=x; __syncthreads(); }
  int pre = csum[c] + ((t>0)?sd[t-1]:0);
  #pragma unroll
  for (int k=0;k<4;k++){
    int i=base+k;
    if (i<n){
      row_ptr[i]=pre; cursor[i]=pre;
      dinv[i]=rsqrtf((float)(v[k]+1));   // +1 self-loop; always >0
      pre+=v[k];
    }
  }
  if (c==0 && t==0) row_ptr[n]=total;
}

__global__ void k_fill(const void* __restrict__ ei, const int* __restrict__ flag,
                       int* __restrict__ cursor, int* __restrict__ colv, int E){
  int e = blockIdx.x*256 + threadIdx.x;
  if (e < E){
    int is32 = *flag;
    int s = idx_at(ei, e, is32), d = idx_at(ei, E + e, is32);
    int pos = atomicAdd(&cursor[d],1);
    colv[pos] = s;
  }
}

// ---- MFMA GEMM with dinv-scale epilogue: G = dinv ⊙ (X @ W) ---------------
// MFMA 16x16x32 bf16; W (128x128, fp32) converted into per-wave register frags.
// A frag: A[m=lane&15][k=quad*8+j]; B frag: B[k=quad*8+j][n=lane&15];
// C/D: col=lane&15, row=quad*4+reg.  (validated: r4 MFMA == r5 fp32-VALU output)
template <typename TIN>
__global__ __launch_bounds__(256) void k_gemm_scale(
    const TIN* __restrict__ X, const float* __restrict__ W,
    const float* __restrict__ dinv, u16* __restrict__ Gout, int nrows)
{
  int lane = threadIdx.x & 63;
  int wv   = threadIdx.x >> 6;
  int n    = lane & 15, quad = lane >> 4;

  short8 bf[8][4];
  #pragma unroll
  for (int t=0;t<8;t++)
    #pragma unroll
    for (int c=0;c<4;c++)
      #pragma unroll
      for (int j=0;j<8;j++)
        bf[t][c][j] = (short)f2bf(W[(c*32 + quad*8 + j)*HD + t*16 + n]);

  int ntiles = (nrows+15)>>4;
  int stride = gridDim.x*4;
  for (int tile = blockIdx.x*4 + wv; tile < ntiles; tile += stride){
    int ra = tile*16 + n;                 // lane's A row (m = lane&15)
    if (ra >= nrows) ra = nrows-1;
    const TIN* xp = X + (size_t)ra*HD + quad*8;
    short8 a[4];
    #pragma unroll
    for (int c=0;c<4;c++) a[c] = load8(xp + c*32);

    f32x4 acc[8];
    #pragma unroll
    for (int t=0;t<8;t++) acc[t] = (f32x4){0.f,0.f,0.f,0.f};
    #pragma unroll
    for (int c=0;c<4;c++)
      #pragma unroll
      for (int t=0;t<8;t++)
        acc[t] = __builtin_amdgcn_mfma_f32_16x16x32_bf16(a[c], bf[t][c], acc[t], 0,0,0);

    float dv[4]; int rw[4];
    #pragma unroll
    for (int r=0;r<4;r++){
      int row = tile*16 + quad*4 + r;
      rw[r]=row; dv[r]=(row<nrows)?dinv[row]:0.f;
    }
    #pragma unroll
    for (int t=0;t<8;t++)
      #pragma unroll
      for (int r=0;r<4;r++){
        int row = rw[r];
        if (row < nrows)
          Gout[(size_t)row*HD + t*16 + n] = f2bf(dv[r]*acc[t][r]);
      }
  }
}

// ---- aggregation: h[i] = relu(dinv[i]*(g[i] + sum_{src} g[src]) + b) ------
// one wave per node; lane handles 2 features (u32 = bf16x2 loads).
__global__ __launch_bounds__(256) void k_aggregate(
    const u16* __restrict__ g, const int* __restrict__ row_ptr,
    const int* __restrict__ colv, const float* __restrict__ dinv,
    const float* __restrict__ bias, u16* __restrict__ h, int n)
{
  int node = blockIdx.x*4 + (threadIdx.x>>6);
  if (node >= n) return;
  int lane = threadIdx.x & 63;
  int off = lane*2;

  u32 u = *reinterpret_cast<const u32*>(g + (size_t)node*HD + off);   // self-loop term
  float ax = bf2f((u16)(u&0xffffu)), ay = bf2f((u16)(u>>16));

  int s = row_ptr[node], e = row_ptr[node+1];
  int i = s;
  for (; i+4<=e; i+=4){
    int s0=colv[i], s1=colv[i+1], s2=colv[i+2], s3=colv[i+3];
    u32 v0=*reinterpret_cast<const u32*>(g+(size_t)s0*HD+off);
    u32 v1=*reinterpret_cast<const u32*>(g+(size_t)s1*HD+off);
    u32 v2=*reinterpret_cast<const u32*>(g+(size_t)s2*HD+off);
    u32 v3=*reinterpret_cast<const u32*>(g+(size_t)s3*HD+off);
    ax += bf2f((u16)(v0&0xffffu)) + bf2f((u16)(v1&0xffffu))
        + bf2f((u16)(v2&0xffffu)) + bf2f((u16)(v3&0xffffu));
    ay += bf2f((u16)(v0>>16)) + bf2f((u16)(v1>>16))
        + bf2f((u16)(v2>>16)) + bf2f((u16)(v3>>16));
  }
  for (; i<e; i++){
    u32 v=*reinterpret_cast<const u32*>(g+(size_t)colv[i]*HD+off);
    ax += bf2f((u16)(v&0xffffu)); ay += bf2f((u16)(v>>16));
  }

  float dv = dinv[node];
  float rx = fmaxf(fmaf(dv, ax, bias[off]),   0.f);
  float ry = fmaxf(fmaf(dv, ay, bias[off+1]), 0.f);
  *reinterpret_cast<u32*>(h + (size_t)node*HD + off) = (u32)f2bf(rx) | ((u32)f2bf(ry)<<16);
}

// ---- global_add_pool, SORT-AGNOSTIC: atomicAdd per node ------------------
__global__ __launch_bounds__(256) void k_pool_atomic(
    const u16* __restrict__ h, const void* __restrict__ batch,
    const int* __restrict__ bflag, float* __restrict__ pooled, int n)
{
  int node = blockIdx.x*4 + (threadIdx.x>>6);
  if (node >= n) return;
  int lane = threadIdx.x & 63;
  int off = lane*2;
  int g = idx_at(batch, node, *bflag);
  u32 v = *reinterpret_cast<const u32*>(h + (size_t)node*HD + off);
  atomicAdd(&pooled[(size_t)g*HD + off],     bf2f((u16)(v&0xffffu)));
  atomicAdd(&pooled[(size_t)g*HD + off + 1], bf2f((u16)(v>>16)));
}

// ---- final linear: out = pooled @ Wl + bl  (FP32 output) ------------------
__global__ void k_final(const float* __restrict__ pooled, const float* __restrict__ Wl,
                        const float* __restrict__ bl, float* __restrict__ out){
  int gid = blockIdx.x, t = threadIdx.x;   // 64 threads
  float acc = bl[t];
  const float* p = pooled + gid*HD;
  #pragma unroll 8
  for (int k=0;k<HD;k++) acc = fmaf(p[k], Wl[k*OUTD + t], acc);
  out[gid*OUTD + t] = acc;
}

extern "C" void kernel_launch(void* const* d_in, const int* in_sizes, int n_in,
                              void* d_out, int out_size, void* d_ws, size_t ws_size,
                              hipStream_t stream)
{
  const float* x   = (const float*)d_in[0];
  const void*  ei  = d_in[1];
  const void*  bat = d_in[2];
  const float* W1  = (const float*)d_in[3];
  const float* b1  = (const float*)d_in[4];
  const float* W2  = (const float*)d_in[5];
  const float* b2  = (const float*)d_in[6];
  const float* Wl  = (const float*)d_in[7];
  const float* bl  = (const float*)d_in[8];
  float* out = (float*)d_out;

  int N = in_sizes[0] / HD;
  int E = in_sizes[1] / 2;
  int G = out_size / OUTD;
  int NCH = (N + 1023) / 1024;

  char* w = (char*)d_ws;
  size_t o = 0;
  auto alloc = [&](size_t b){ void* p = w + o; o += (b + 255) & ~(size_t)255; return p; };
  int*   cnt     = (int*)  alloc((size_t)N*4);
  int*   row_ptr = (int*)  alloc((size_t)(N+1)*4);
  int*   cursor  = (int*)  alloc((size_t)N*4);
  int*   csum    = (int*)  alloc((size_t)NCH*4);
  int*   colv    = (int*)  alloc((size_t)E*4);
  float* dinv    = (float*)alloc((size_t)N*4);
  u16*   gbuf    = (u16*)  alloc((size_t)N*HD*2);
  u16*   hbuf    = (u16*)  alloc((size_t)N*HD*2);
  float* pooled  = (float*)alloc((size_t)G*HD*4);
  int*   eflag   = (int*)  alloc(256);
  int*   bflag   = (int*)  alloc(256);
  (void)n_in;

  if (o > ws_size){
    // workspace too small — emit zeros as a distinctive diagnostic signal
    k_zero_out<<<(out_size+255)/256, 256, 0, stream>>>(out, out_size);
    return;
  }

  // detect int32 vs int64 index delivery (flag: 1 = int32, 0 = int64)
  int npairs_e = 4096; if (npairs_e > E) npairs_e = E;
  int npairs_b = 4096; if (npairs_b > N/2) npairs_b = N/2;
  (void)hipMemsetAsync(eflag, 0, 4, stream);
  (void)hipMemsetAsync(bflag, 0, 4, stream);
  k_detect <<<(npairs_e+255)/256, 256, 0, stream>>>((const u32*)ei, eflag, npairs_e);
  k_detect <<<(npairs_b+255)/256, 256, 0, stream>>>((const u32*)bat, bflag, npairs_b);

  // CSR build + degrees
  (void)hipMemsetAsync(cnt, 0, (size_t)N*4, stream);
  k_count      <<<(E+255)/256, 256, 0, stream>>>(ei, eflag, cnt, E);
  k_chunk_sums <<<NCH, 256, 0, stream>>>(cnt, csum, N);
  k_scan_serial<<<1, 64, 0, stream>>>(csum, NCH);
  k_scan_chunks<<<NCH, 256, 0, stream>>>(cnt, csum, row_ptr, cursor, dinv, N, E);
  k_fill       <<<(E+255)/256, 256, 0, stream>>>(ei, eflag, cursor, colv, E);

  // layer 1
  k_gemm_scale<float><<<512, 256, 0, stream>>>(x, W1, dinv, gbuf, N);
  k_aggregate <<<(N+3)/4, 256, 0, stream>>>(gbuf, row_ptr, colv, dinv, b1, hbuf, N);
  // layer 2
  k_gemm_scale<u16>  <<<512, 256, 0, stream>>>(hbuf, W2, dinv, gbuf, N);
  k_aggregate <<<(N+3)/4, 256, 0, stream>>>(gbuf, row_ptr, colv, dinv, b2, hbuf, N);
  // pool (sort-agnostic) + final linear
  (void)hipMemsetAsync(pooled, 0, (size_t)G*HD*4, stream);
  k_pool_atomic<<<(N+3)/4, 256, 0, stream>>>(hbuf, bat, bflag, pooled, N);
  k_final      <<<G, OUTD, 0, stream>>>(pooled, Wl, bl, out);
}

// Round 8
// 592.381 us; speedup vs baseline: 1.1060x; 1.1060x over previous
//
#include <hip/hip_runtime.h>
#include <hip/hip_bf16.h>

typedef unsigned short u16;
typedef unsigned int   u32;
typedef long long      i64;
typedef __attribute__((ext_vector_type(8))) short short8;  // 8 bf16 raw
typedef __attribute__((ext_vector_type(4))) float f32x4;

#define HD 128   // hidden / input feature dim
#define OUTD 64  // final output dim
#define FILL_NB 8        // dst buckets == XCD count
#define FILL_CHUNK 16384 // edges per block-chunk in bucketed fill

__device__ __forceinline__ float bf2f(u16 u){ union{u32 i; float f;} x; x.i=((u32)u)<<16; return x.f; }
__device__ __forceinline__ u16 f2bf(float f){ __hip_bfloat16 h=__float2bfloat16(f); return *reinterpret_cast<u16*>(&h); }

// 8-element bf16 fragment loader: fp32 source converts, bf16 source is direct.
__device__ __forceinline__ short8 load8(const float* p){
  f32x4 lo = *reinterpret_cast<const f32x4*>(p);
  f32x4 hi = *reinterpret_cast<const f32x4*>(p + 4);
  short8 r;
  #pragma unroll
  for (int j=0;j<4;j++){ r[j]=(short)f2bf(lo[j]); r[4+j]=(short)f2bf(hi[j]); }
  return r;
}
__device__ __forceinline__ short8 load8(const u16* p){
  return *reinterpret_cast<const short8*>(p);
}

// index fetch that handles int32-vs-int64 delivery (flag: 1 = int32, 0 = int64)
__device__ __forceinline__ int idx_at(const void* p, int i, int is32){
  return is32 ? ((const int*)p)[i] : (int)((const i64*)p)[i];
}

// ---- dtype detect: int64 buffers of nonneg values have all odd words == 0 --
__global__ void k_detect(const u32* __restrict__ w, int* __restrict__ flag, int npairs){
  int i = blockIdx.x*256 + threadIdx.x;
  if (i < npairs && w[2*i+1] != 0) atomicOr(flag, 1);   // nonzero odd word -> int32
}

// ---- zero-fill output (ws-too-small fallback signal) ----------------------
__global__ void k_zero_out(float* __restrict__ out, int n){
  int i = blockIdx.x*256 + threadIdx.x;
  if (i < n) out[i] = 0.f;
}

// ---- CSR build ------------------------------------------------------------
__global__ void k_count(const void* __restrict__ ei, const int* __restrict__ flag,
                        int* __restrict__ cnt, int E){
  int e = blockIdx.x*256 + threadIdx.x;
  if (e < E){
    int d = idx_at(ei, E + e, *flag);   // dst = row 1
    atomicAdd(&cnt[d], 1);
  }
}

__global__ void k_chunk_sums(const int* __restrict__ cnt, int* __restrict__ csum, int n){
  __shared__ int sd[256];
  int c=blockIdx.x, t=threadIdx.x;
  int base=c*1024+t*4, s=0;
  #pragma unroll
  for (int k=0;k<4;k++){ int i=base+k; if(i<n) s+=cnt[i]; }
  sd[t]=s; __syncthreads();
  for (int o=128;o>0;o>>=1){ if(t<o) sd[t]+=sd[t+o]; __syncthreads(); }
  if (t==0) csum[c]=sd[0];
}

// one-block exclusive scan of chunk totals (m <= 1024)
__global__ void k_scan_totals(int* csum, int m){
  __shared__ int sd[256];
  int t = threadIdx.x;
  int v[4]; int s=0;
  #pragma unroll
  for (int k=0;k<4;k++){ int i=t*4+k; v[k]=(i<m)?csum[i]:0; s+=v[k]; }
  sd[t]=s; __syncthreads();
  for (int o=1;o<256;o<<=1){ int x=(t>=o)?sd[t-o]:0; __syncthreads(); sd[t]+=x; __syncthreads(); }
  int pre = (t>0)?sd[t-1]:0;
  #pragma unroll
  for (int k=0;k<4;k++){ int i=t*4+k; if(i<m){ int vv=v[k]; csum[i]=pre; pre+=vv; } }
}

__global__ void k_scan_chunks(const int* __restrict__ cnt, const int* __restrict__ csum,
                              int* __restrict__ row_ptr, int* __restrict__ cursor,
                              float* __restrict__ dinv, int n, int total){
  __shared__ int sd[256];
  int c=blockIdx.x, t=threadIdx.x;
  int base=c*1024+t*4;
  int v[4], s=0;
  #pragma unroll
  for (int k=0;k<4;k++){ int i=base+k; v[k]=(i<n)?cnt[i]:0; s+=v[k]; }
  sd[t]=s; __syncthreads();
  for (int o=1;o<256;o<<=1){ int x=(t>=o)?sd[t-o]:0; __syncthreads(); sd[t]+=x; __syncthreads(); }
  int pre = csum[c] + ((t>0)?sd[t-1]:0);
  #pragma unroll
  for (int k=0;k<4;k++){
    int i=base+k;
    if (i<n){
      row_ptr[i]=pre; cursor[i]=pre;
      dinv[i]=rsqrtf((float)(v[k]+1));   // +1 self-loop; always >0
      pre+=v[k];
    }
  }
  if (c==0 && t==0) row_ptr[n]=total;
}

// ---- bucketed CSR fill: bucket = blockIdx%8 tracks XCD round-robin --------
// colv window of a dst-bucket is contiguous (~E/8*4 B) -> stays in that
// XCD's L2, lines fully filled before writeback (was: 105 MB scattered WB).
__global__ __launch_bounds__(256) void k_fill_bucketed(
    const void* __restrict__ ei, const int* __restrict__ flag,
    int* __restrict__ cursor, int* __restrict__ colv, int E, int N)
{
  int bucket = blockIdx.x % FILL_NB;
  int chunk  = blockIdx.x / FILL_NB;
  int lo = (int)((i64)bucket     * N / FILL_NB);
  int hi = (int)((i64)(bucket+1) * N / FILL_NB);
  int base = chunk * FILL_CHUNK;
  int end  = base + FILL_CHUNK; if (end > E) end = E;
  int is32 = *flag;
  for (int e = base + threadIdx.x; e < end; e += 256){
    int d = idx_at(ei, E + e, is32);
    if (d >= lo && d < hi){
      int s = idx_at(ei, e, is32);
      int pos = atomicAdd(&cursor[d], 1);
      colv[pos] = s;
    }
  }
}

// ---- MFMA GEMM with dinv-scale epilogue: G = dinv ⊙ (X @ W) ---------------
// MFMA 16x16x32 bf16; W (128x128, fp32) converted into per-wave register frags.
// A frag: A[m=lane&15][k=quad*8+j]; B frag: B[k=quad*8+j][n=lane&15];
// C/D: col=lane&15, row=quad*4+reg.  (validated vs fp32-VALU in r5/r7)
template <typename TIN>
__global__ __launch_bounds__(256) void k_gemm_scale(
    const TIN* __restrict__ X, const float* __restrict__ W,
    const float* __restrict__ dinv, u16* __restrict__ Gout, int nrows)
{
  int lane = threadIdx.x & 63;
  int wv   = threadIdx.x >> 6;
  int n    = lane & 15, quad = lane >> 4;

  short8 bf[8][4];
  #pragma unroll
  for (int t=0;t<8;t++)
    #pragma unroll
    for (int c=0;c<4;c++)
      #pragma unroll
      for (int j=0;j<8;j++)
        bf[t][c][j] = (short)f2bf(W[(c*32 + quad*8 + j)*HD + t*16 + n]);

  int ntiles = (nrows+15)>>4;
  int stride = gridDim.x*4;
  for (int tile = blockIdx.x*4 + wv; tile < ntiles; tile += stride){
    int ra = tile*16 + n;                 // lane's A row (m = lane&15)
    if (ra >= nrows) ra = nrows-1;
    const TIN* xp = X + (size_t)ra*HD + quad*8;
    short8 a[4];
    #pragma unroll
    for (int c=0;c<4;c++) a[c] = load8(xp + c*32);

    f32x4 acc[8];
    #pragma unroll
    for (int t=0;t<8;t++) acc[t] = (f32x4){0.f,0.f,0.f,0.f};
    #pragma unroll
    for (int c=0;c<4;c++)
      #pragma unroll
      for (int t=0;t<8;t++)
        acc[t] = __builtin_amdgcn_mfma_f32_16x16x32_bf16(a[c], bf[t][c], acc[t], 0,0,0);

    float dv[4]; int rw[4];
    #pragma unroll
    for (int r=0;r<4;r++){
      int row = tile*16 + quad*4 + r;
      rw[r]=row; dv[r]=(row<nrows)?dinv[row]:0.f;
    }
    #pragma unroll
    for (int t=0;t<8;t++)
      #pragma unroll
      for (int r=0;r<4;r++){
        int row = rw[r];
        if (row < nrows)
          Gout[(size_t)row*HD + t*16 + n] = f2bf(dv[r]*acc[t][r]);
      }
  }
}

// ---- aggregation: h[i] = relu(dinv[i]*(g[i] + sum_{src} g[src]) + b) ------
// one wave per node; lane handles 2 features (u32 = bf16x2 loads).
__global__ __launch_bounds__(256) void k_aggregate(
    const u16* __restrict__ g, const int* __restrict__ row_ptr,
    const int* __restrict__ colv, const float* __restrict__ dinv,
    const float* __restrict__ bias, u16* __restrict__ h, int n)
{
  int node = blockIdx.x*4 + (threadIdx.x>>6);
  if (node >= n) return;
  int lane = threadIdx.x & 63;
  int off = lane*2;

  u32 u = *reinterpret_cast<const u32*>(g + (size_t)node*HD + off);   // self-loop term
  float ax = bf2f((u16)(u&0xffffu)), ay = bf2f((u16)(u>>16));

  int s = row_ptr[node], e = row_ptr[node+1];
  int i = s;
  for (; i+4<=e; i+=4){
    int s0=colv[i], s1=colv[i+1], s2=colv[i+2], s3=colv[i+3];
    u32 v0=*reinterpret_cast<const u32*>(g+(size_t)s0*HD+off);
    u32 v1=*reinterpret_cast<const u32*>(g+(size_t)s1*HD+off);
    u32 v2=*reinterpret_cast<const u32*>(g+(size_t)s2*HD+off);
    u32 v3=*reinterpret_cast<const u32*>(g+(size_t)s3*HD+off);
    ax += bf2f((u16)(v0&0xffffu)) + bf2f((u16)(v1&0xffffu))
        + bf2f((u16)(v2&0xffffu)) + bf2f((u16)(v3&0xffffu));
    ay += bf2f((u16)(v0>>16)) + bf2f((u16)(v1>>16))
        + bf2f((u16)(v2>>16)) + bf2f((u16)(v3>>16));
  }
  for (; i<e; i++){
    u32 v=*reinterpret_cast<const u32*>(g+(size_t)colv[i]*HD+off);
    ax += bf2f((u16)(v&0xffffu)); ay += bf2f((u16)(v>>16));
  }

  float dv = dinv[node];
  float rx = fmaxf(fmaf(dv, ax, bias[off]),   0.f);
  float ry = fmaxf(fmaf(dv, ay, bias[off+1]), 0.f);
  *reinterpret_cast<u32*>(h + (size_t)node*HD + off) = (u32)f2bf(rx) | ((u32)f2bf(ry)<<16);
}

// ---- global_add_pool, SORT-AGNOSTIC: atomicAdd per node ------------------
__global__ __launch_bounds__(256) void k_pool_atomic(
    const u16* __restrict__ h, const void* __restrict__ batch,
    const int* __restrict__ bflag, float* __restrict__ pooled, int n)
{
  int node = blockIdx.x*4 + (threadIdx.x>>6);
  if (node >= n) return;
  int lane = threadIdx.x & 63;
  int off = lane*2;
  int g = idx_at(batch, node, *bflag);
  u32 v = *reinterpret_cast<const u32*>(h + (size_t)node*HD + off);
  atomicAdd(&pooled[(size_t)g*HD + off],     bf2f((u16)(v&0xffffu)));
  atomicAdd(&pooled[(size_t)g*HD + off + 1], bf2f((u16)(v>>16)));
}

// ---- final linear: out = pooled @ Wl + bl  (FP32 output) ------------------
__global__ void k_final(const float* __restrict__ pooled, const float* __restrict__ Wl,
                        const float* __restrict__ bl, float* __restrict__ out){
  int gid = blockIdx.x, t = threadIdx.x;   // 64 threads
  float acc = bl[t];
  const float* p = pooled + gid*HD;
  #pragma unroll 8
  for (int k=0;k<HD;k++) acc = fmaf(p[k], Wl[k*OUTD + t], acc);
  out[gid*OUTD + t] = acc;
}

extern "C" void kernel_launch(void* const* d_in, const int* in_sizes, int n_in,
                              void* d_out, int out_size, void* d_ws, size_t ws_size,
                              hipStream_t stream)
{
  const float* x   = (const float*)d_in[0];
  const void*  ei  = d_in[1];
  const void*  bat = d_in[2];
  const float* W1  = (const float*)d_in[3];
  const float* b1  = (const float*)d_in[4];
  const float* W2  = (const float*)d_in[5];
  const float* b2  = (const float*)d_in[6];
  const float* Wl  = (const float*)d_in[7];
  const float* bl  = (const float*)d_in[8];
  float* out = (float*)d_out;

  int N = in_sizes[0] / HD;
  int E = in_sizes[1] / 2;
  int G = out_size / OUTD;
  int NCH = (N + 1023) / 1024;

  char* w = (char*)d_ws;
  size_t o = 0;
  auto alloc = [&](size_t b){ void* p = w + o; o += (b + 255) & ~(size_t)255; return p; };
  int*   cnt     = (int*)  alloc((size_t)N*4);
  int*   row_ptr = (int*)  alloc((size_t)(N+1)*4);
  int*   cursor  = (int*)  alloc((size_t)N*4);
  int*   csum    = (int*)  alloc((size_t)NCH*4);
  int*   colv    = (int*)  alloc((size_t)E*4);
  float* dinv    = (float*)alloc((size_t)N*4);
  u16*   gbuf    = (u16*)  alloc((size_t)N*HD*2);
  u16*   hbuf    = (u16*)  alloc((size_t)N*HD*2);
  float* pooled  = (float*)alloc((size_t)G*HD*4);
  int*   eflag   = (int*)  alloc(256);
  int*   bflag   = (int*)  alloc(256);
  (void)n_in;

  if (o > ws_size){
    // workspace too small — emit zeros as a distinctive diagnostic signal
    k_zero_out<<<(out_size+255)/256, 256, 0, stream>>>(out, out_size);
    return;
  }

  // detect int32 vs int64 index delivery (flag: 1 = int32, 0 = int64)
  int npairs_e = 4096; if (npairs_e > E) npairs_e = E;
  int npairs_b = 4096; if (npairs_b > N/2) npairs_b = N/2;
  (void)hipMemsetAsync(eflag, 0, 4, stream);
  (void)hipMemsetAsync(bflag, 0, 4, stream);
  k_detect <<<(npairs_e+255)/256, 256, 0, stream>>>((const u32*)ei, eflag, npairs_e);
  k_detect <<<(npairs_b+255)/256, 256, 0, stream>>>((const u32*)bat, bflag, npairs_b);

  // CSR build + degrees
  (void)hipMemsetAsync(cnt, 0, (size_t)N*4, stream);
  k_count      <<<(E+255)/256, 256, 0, stream>>>(ei, eflag, cnt, E);
  k_chunk_sums <<<NCH, 256, 0, stream>>>(cnt, csum, N);
  k_scan_totals<<<1, 256, 0, stream>>>(csum, NCH);
  k_scan_chunks<<<NCH, 256, 0, stream>>>(cnt, csum, row_ptr, cursor, dinv, N, E);
  int fill_chunks = (E + FILL_CHUNK - 1) / FILL_CHUNK;
  k_fill_bucketed<<<fill_chunks*FILL_NB, 256, 0, stream>>>(ei, eflag, cursor, colv, E, N);

  // layer 1
  k_gemm_scale<float><<<512, 256, 0, stream>>>(x, W1, dinv, gbuf, N);
  k_aggregate <<<(N+3)/4, 256, 0, stream>>>(gbuf, row_ptr, colv, dinv, b1, hbuf, N);
  // layer 2
  k_gemm_scale<u16>  <<<512, 256, 0, stream>>>(hbuf, W2, dinv, gbuf, N);
  k_aggregate <<<(N+3)/4, 256, 0, stream>>>(gbuf, row_ptr, colv, dinv, b2, hbuf, N);
  // pool (sort-agnostic) + final linear
  (void)hipMemsetAsync(pooled, 0, (size_t)G*HD*4, stream);
  k_pool_atomic<<<(N+3)/4, 256, 0, stream>>>(hbuf, bat, bflag, pooled, N);
  k_final      <<<G, OUTD, 0, stream>>>(pooled, Wl, bl, out);
}

// Round 9
// 573.113 us; speedup vs baseline: 1.1431x; 1.0336x over previous
//
#include <hip/hip_runtime.h>
#include <hip/hip_bf16.h>

typedef unsigned short u16;
typedef unsigned int   u32;
typedef long long      i64;
typedef __attribute__((ext_vector_type(8))) short short8;  // 8 bf16 raw
typedef __attribute__((ext_vector_type(4))) float f32x4;

#define HD 128   // hidden / input feature dim
#define OUTD 64  // final output dim
#define FILL_NB 8        // dst buckets == XCD count
#define FILL_CHUNK 16384 // edges per block-chunk in bucketed fill

__device__ __forceinline__ float bf2f(u16 u){ union{u32 i; float f;} x; x.i=((u32)u)<<16; return x.f; }
__device__ __forceinline__ u16 f2bf(float f){ __hip_bfloat16 h=__float2bfloat16(f); return *reinterpret_cast<u16*>(&h); }

// 8-element bf16 fragment loader: fp32 source converts, bf16 source is direct.
__device__ __forceinline__ short8 load8(const float* p){
  f32x4 lo = *reinterpret_cast<const f32x4*>(p);
  f32x4 hi = *reinterpret_cast<const f32x4*>(p + 4);
  short8 r;
  #pragma unroll
  for (int j=0;j<4;j++){ r[j]=(short)f2bf(lo[j]); r[4+j]=(short)f2bf(hi[j]); }
  return r;
}
__device__ __forceinline__ short8 load8(const u16* p){
  return *reinterpret_cast<const short8*>(p);
}

// index fetch that handles int32-vs-int64 delivery (flag: 1 = int32, 0 = int64)
__device__ __forceinline__ int idx_at(const void* p, int i, int is32){
  return is32 ? ((const int*)p)[i] : (int)((const i64*)p)[i];
}

// ---- dtype detect: int64 buffers of nonneg values have all odd words == 0 --
__global__ void k_detect(const u32* __restrict__ w, int* __restrict__ flag, int npairs){
  int i = blockIdx.x*256 + threadIdx.x;
  if (i < npairs && w[2*i+1] != 0) atomicOr(flag, 1);   // nonzero odd word -> int32
}

// ---- sortedness check for batch -------------------------------------------
__global__ void k_check_sorted(const void* __restrict__ batch, const int* __restrict__ bflag,
                               int* __restrict__ sflag, int n){
  int i = blockIdx.x*256 + threadIdx.x;
  if (i < n-1){
    int is32 = *bflag;
    if (idx_at(batch, i, is32) > idx_at(batch, i+1, is32)) atomicOr(sflag, 1);
  }
}

// ---- zero-fill output (ws-too-small fallback signal) ----------------------
__global__ void k_zero_out(float* __restrict__ out, int n){
  int i = blockIdx.x*256 + threadIdx.x;
  if (i < n) out[i] = 0.f;
}

// ---- CSR build ------------------------------------------------------------
__global__ void k_count(const void* __restrict__ ei, const int* __restrict__ flag,
                        int* __restrict__ cnt, int E){
  int e = blockIdx.x*256 + threadIdx.x;
  if (e < E){
    int d = idx_at(ei, E + e, *flag);   // dst = row 1
    atomicAdd(&cnt[d], 1);
  }
}

__global__ void k_chunk_sums(const int* __restrict__ cnt, int* __restrict__ csum, int n){
  __shared__ int sd[256];
  int c=blockIdx.x, t=threadIdx.x;
  int base=c*1024+t*4, s=0;
  #pragma unroll
  for (int k=0;k<4;k++){ int i=base+k; if(i<n) s+=cnt[i]; }
  sd[t]=s; __syncthreads();
  for (int o=128;o>0;o>>=1){ if(t<o) sd[t]+=sd[t+o]; __syncthreads(); }
  if (t==0) csum[c]=sd[0];
}

// one-block exclusive scan of chunk totals (m <= 1024)
__global__ void k_scan_totals(int* csum, int m){
  __shared__ int sd[256];
  int t = threadIdx.x;
  int v[4]; int s=0;
  #pragma unroll
  for (int k=0;k<4;k++){ int i=t*4+k; v[k]=(i<m)?csum[i]:0; s+=v[k]; }
  sd[t]=s; __syncthreads();
  for (int o=1;o<256;o<<=1){ int x=(t>=o)?sd[t-o]:0; __syncthreads(); sd[t]+=x; __syncthreads(); }
  int pre = (t>0)?sd[t-1]:0;
  #pragma unroll
  for (int k=0;k<4;k++){ int i=t*4+k; if(i<m){ int vv=v[k]; csum[i]=pre; pre+=vv; } }
}

__global__ void k_scan_chunks(const int* __restrict__ cnt, const int* __restrict__ csum,
                              int* __restrict__ row_ptr, int* __restrict__ cursor,
                              float* __restrict__ dinv, int n, int total){
  __shared__ int sd[256];
  int c=blockIdx.x, t=threadIdx.x;
  int base=c*1024+t*4;
  int v[4], s=0;
  #pragma unroll
  for (int k=0;k<4;k++){ int i=base+k; v[k]=(i<n)?cnt[i]:0; s+=v[k]; }
  sd[t]=s; __syncthreads();
  for (int o=1;o<256;o<<=1){ int x=(t>=o)?sd[t-o]:0; __syncthreads(); sd[t]+=x; __syncthreads(); }
  int pre = csum[c] + ((t>0)?sd[t-1]:0);
  #pragma unroll
  for (int k=0;k<4;k++){
    int i=base+k;
    if (i<n){
      row_ptr[i]=pre; cursor[i]=pre;
      dinv[i]=rsqrtf((float)(v[k]+1));   // +1 self-loop; always >0
      pre+=v[k];
    }
  }
  if (c==0 && t==0) row_ptr[n]=total;
}

// ---- bucketed CSR fill: bucket = blockIdx%8 tracks XCD round-robin --------
__global__ __launch_bounds__(256) void k_fill_bucketed(
    const void* __restrict__ ei, const int* __restrict__ flag,
    int* __restrict__ cursor, int* __restrict__ colv, int E, int N)
{
  int bucket = blockIdx.x % FILL_NB;
  int chunk  = blockIdx.x / FILL_NB;
  int lo = (int)((i64)bucket     * N / FILL_NB);
  int hi = (int)((i64)(bucket+1) * N / FILL_NB);
  int base = chunk * FILL_CHUNK;
  int end  = base + FILL_CHUNK; if (end > E) end = E;
  int is32 = *flag;
  for (int e = base + threadIdx.x; e < end; e += 256){
    int d = idx_at(ei, E + e, is32);
    if (d >= lo && d < hi){
      int s = idx_at(ei, e, is32);
      int pos = atomicAdd(&cursor[d], 1);
      colv[pos] = s;
    }
  }
}

// ---- MFMA GEMM with dinv-scale epilogue: G = dinv ⊙ (X @ W) ---------------
template <typename TIN>
__global__ __launch_bounds__(256) void k_gemm_scale(
    const TIN* __restrict__ X, const float* __restrict__ W,
    const float* __restrict__ dinv, u16* __restrict__ Gout, int nrows)
{
  int lane = threadIdx.x & 63;
  int wv   = threadIdx.x >> 6;
  int n    = lane & 15, quad = lane >> 4;

  short8 bf[8][4];
  #pragma unroll
  for (int t=0;t<8;t++)
    #pragma unroll
    for (int c=0;c<4;c++)
      #pragma unroll
      for (int j=0;j<8;j++)
        bf[t][c][j] = (short)f2bf(W[(c*32 + quad*8 + j)*HD + t*16 + n]);

  int ntiles = (nrows+15)>>4;
  int stride = gridDim.x*4;
  for (int tile = blockIdx.x*4 + wv; tile < ntiles; tile += stride){
    int ra = tile*16 + n;                 // lane's A row (m = lane&15)
    if (ra >= nrows) ra = nrows-1;
    const TIN* xp = X + (size_t)ra*HD + quad*8;
    short8 a[4];
    #pragma unroll
    for (int c=0;c<4;c++) a[c] = load8(xp + c*32);

    f32x4 acc[8];
    #pragma unroll
    for (int t=0;t<8;t++) acc[t] = (f32x4){0.f,0.f,0.f,0.f};
    #pragma unroll
    for (int c=0;c<4;c++)
      #pragma unroll
      for (int t=0;t<8;t++)
        acc[t] = __builtin_amdgcn_mfma_f32_16x16x32_bf16(a[c], bf[t][c], acc[t], 0,0,0);

    float dv[4]; int rw[4];
    #pragma unroll
    for (int r=0;r<4;r++){
      int row = tile*16 + quad*4 + r;
      rw[r]=row; dv[r]=(row<nrows)?dinv[row]:0.f;
    }
    #pragma unroll
    for (int t=0;t<8;t++)
      #pragma unroll
      for (int r=0;r<4;r++){
        int row = rw[r];
        if (row < nrows)
          Gout[(size_t)row*HD + t*16 + n] = f2bf(dv[r]*acc[t][r]);
      }
  }
}

// ---- aggregation: h[i] = relu(dinv[i]*(g[i] + sum_{src} g[src]) + b) ------
__global__ __launch_bounds__(256) void k_aggregate(
    const u16* __restrict__ g, const int* __restrict__ row_ptr,
    const int* __restrict__ colv, const float* __restrict__ dinv,
    const float* __restrict__ bias, u16* __restrict__ h, int n)
{
  int node = blockIdx.x*4 + (threadIdx.x>>6);
  if (node >= n) return;
  int lane = threadIdx.x & 63;
  int off = lane*2;

  u32 u = *reinterpret_cast<const u32*>(g + (size_t)node*HD + off);   // self-loop term
  float ax = bf2f((u16)(u&0xffffu)), ay = bf2f((u16)(u>>16));

  int s = row_ptr[node], e = row_ptr[node+1];
  int i = s;
  for (; i+4<=e; i+=4){
    int s0=colv[i], s1=colv[i+1], s2=colv[i+2], s3=colv[i+3];
    u32 v0=*reinterpret_cast<const u32*>(g+(size_t)s0*HD+off);
    u32 v1=*reinterpret_cast<const u32*>(g+(size_t)s1*HD+off);
    u32 v2=*reinterpret_cast<const u32*>(g+(size_t)s2*HD+off);
    u32 v3=*reinterpret_cast<const u32*>(g+(size_t)s3*HD+off);
    ax += bf2f((u16)(v0&0xffffu)) + bf2f((u16)(v1&0xffffu))
        + bf2f((u16)(v2&0xffffu)) + bf2f((u16)(v3&0xffffu));
    ay += bf2f((u16)(v0>>16)) + bf2f((u16)(v1>>16))
        + bf2f((u16)(v2>>16)) + bf2f((u16)(v3>>16));
  }
  for (; i<e; i++){
    u32 v=*reinterpret_cast<const u32*>(g+(size_t)colv[i]*HD+off);
    ax += bf2f((u16)(v&0xffffu)); ay += bf2f((u16)(v>>16));
  }

  float dv = dinv[node];
  float rx = fmaxf(fmaf(dv, ax, bias[off]),   0.f);
  float ry = fmaxf(fmaf(dv, ay, bias[off+1]), 0.f);
  *reinterpret_cast<u32*>(h + (size_t)node*HD + off) = (u32)f2bf(rx) | ((u32)f2bf(ry)<<16);
}

// ---- global_add_pool, sorted path: one block per graph, no atomics --------
__device__ __forceinline__ int lowerb(const void* a, int is32, int n, int key){
  int lo=0, hi=n;
  while (lo<hi){
    int mid=(lo+hi)>>1;
    if (idx_at(a, mid, is32) < key) lo=mid+1; else hi=mid;
  }
  return lo;
}

__global__ __launch_bounds__(128) void k_pool_sorted(
    const u16* __restrict__ h, const void* __restrict__ batch,
    const int* __restrict__ bflag, const int* __restrict__ sflag,
    float* __restrict__ pooled, int n)
{
  if (*sflag) return;                       // unsorted -> atomic path handles it
  int gid = blockIdx.x, t = threadIdx.x;    // 128 threads, one feature each
  int is32 = *bflag;
  int lo = lowerb(batch, is32, n, gid), hi = lowerb(batch, is32, n, gid+1);
  float acc = 0.f;
  for (int i=lo;i<hi;i++) acc += bf2f(h[(size_t)i*HD + t]);
  pooled[(size_t)gid*HD + t] = acc;
}

// ---- global_add_pool, fallback: atomicAdd per node (any ordering) ---------
__global__ __launch_bounds__(256) void k_pool_atomic(
    const u16* __restrict__ h, const void* __restrict__ batch,
    const int* __restrict__ bflag, const int* __restrict__ sflag,
    float* __restrict__ pooled, int n)
{
  if (!*sflag) return;                      // sorted path already did it
  int node = blockIdx.x*4 + (threadIdx.x>>6);
  if (node >= n) return;
  int lane = threadIdx.x & 63;
  int off = lane*2;
  int g = idx_at(batch, node, *bflag);
  u32 v = *reinterpret_cast<const u32*>(h + (size_t)node*HD + off);
  atomicAdd(&pooled[(size_t)g*HD + off],     bf2f((u16)(v&0xffffu)));
  atomicAdd(&pooled[(size_t)g*HD + off + 1], bf2f((u16)(v>>16)));
}

// ---- final linear: out = pooled @ Wl + bl  (FP32 output) ------------------
__global__ void k_final(const float* __restrict__ pooled, const float* __restrict__ Wl,
                        const float* __restrict__ bl, float* __restrict__ out){
  int gid = blockIdx.x, t = threadIdx.x;   // 64 threads
  float acc = bl[t];
  const float* p = pooled + gid*HD;
  #pragma unroll 8
  for (int k=0;k<HD;k++) acc = fmaf(p[k], Wl[k*OUTD + t], acc);
  out[gid*OUTD + t] = acc;
}

extern "C" void kernel_launch(void* const* d_in, const int* in_sizes, int n_in,
                              void* d_out, int out_size, void* d_ws, size_t ws_size,
                              hipStream_t stream)
{
  const float* x   = (const float*)d_in[0];
  const void*  ei  = d_in[1];
  const void*  bat = d_in[2];
  const float* W1  = (const float*)d_in[3];
  const float* b1  = (const float*)d_in[4];
  const float* W2  = (const float*)d_in[5];
  const float* b2  = (const float*)d_in[6];
  const float* Wl  = (const float*)d_in[7];
  const float* bl  = (const float*)d_in[8];
  float* out = (float*)d_out;

  int N = in_sizes[0] / HD;
  int E = in_sizes[1] / 2;
  int G = out_size / OUTD;
  int NCH = (N + 1023) / 1024;

  char* w = (char*)d_ws;
  size_t o = 0;
  auto alloc = [&](size_t b){ void* p = w + o; o += (b + 255) & ~(size_t)255; return p; };
  int*   cnt     = (int*)  alloc((size_t)N*4);
  int*   row_ptr = (int*)  alloc((size_t)(N+1)*4);
  int*   cursor  = (int*)  alloc((size_t)N*4);
  int*   csum    = (int*)  alloc((size_t)NCH*4);
  int*   colv    = (int*)  alloc((size_t)E*4);
  float* dinv    = (float*)alloc((size_t)N*4);
  u16*   gbuf    = (u16*)  alloc((size_t)N*HD*2);
  u16*   hbuf    = (u16*)  alloc((size_t)N*HD*2);
  float* pooled  = (float*)alloc((size_t)G*HD*4);
  int*   eflag   = (int*)  alloc(256);
  int*   bflag   = (int*)  alloc(256);
  int*   sflag   = (int*)  alloc(256);
  (void)n_in;

  if (o > ws_size){
    k_zero_out<<<(out_size+255)/256, 256, 0, stream>>>(out, out_size);
    return;
  }

  // detect int32 vs int64 index delivery (flag: 1 = int32, 0 = int64)
  int npairs_e = 4096; if (npairs_e > E) npairs_e = E;
  int npairs_b = 4096; if (npairs_b > N/2) npairs_b = N/2;
  (void)hipMemsetAsync(eflag, 0, 4, stream);
  (void)hipMemsetAsync(bflag, 0, 4, stream);
  (void)hipMemsetAsync(sflag, 0, 4, stream);
  k_detect <<<(npairs_e+255)/256, 256, 0, stream>>>((const u32*)ei, eflag, npairs_e);
  k_detect <<<(npairs_b+255)/256, 256, 0, stream>>>((const u32*)bat, bflag, npairs_b);
  k_check_sorted<<<(N+255)/256, 256, 0, stream>>>(bat, bflag, sflag, N);

  // CSR build + degrees
  (void)hipMemsetAsync(cnt, 0, (size_t)N*4, stream);
  k_count      <<<(E+255)/256, 256, 0, stream>>>(ei, eflag, cnt, E);
  k_chunk_sums <<<NCH, 256, 0, stream>>>(cnt, csum, N);
  k_scan_totals<<<1, 256, 0, stream>>>(csum, NCH);
  k_scan_chunks<<<NCH, 256, 0, stream>>>(cnt, csum, row_ptr, cursor, dinv, N, E);
  int fill_chunks = (E + FILL_CHUNK - 1) / FILL_CHUNK;
  k_fill_bucketed<<<fill_chunks*FILL_NB, 256, 0, stream>>>(ei, eflag, cursor, colv, E, N);

  // layer 1
  k_gemm_scale<float><<<512, 256, 0, stream>>>(x, W1, dinv, gbuf, N);
  k_aggregate <<<(N+3)/4, 256, 0, stream>>>(gbuf, row_ptr, colv, dinv, b1, hbuf, N);
  // layer 2
  k_gemm_scale<u16>  <<<512, 256, 0, stream>>>(hbuf, W2, dinv, gbuf, N);
  k_aggregate <<<(N+3)/4, 256, 0, stream>>>(gbuf, row_ptr, colv, dinv, b2, hbuf, N);
  // pool: sorted fast path + atomic fallback (exactly one does work)
  (void)hipMemsetAsync(pooled, 0, (size_t)G*HD*4, stream);
  k_pool_sorted<<<G, 128, 0, stream>>>(hbuf, bat, bflag, sflag, pooled, N);
  k_pool_atomic<<<(N+3)/4, 256, 0, stream>>>(hbuf, bat, bflag, sflag, pooled, N);
  k_final      <<<G, OUTD, 0, stream>>>(pooled, Wl, bl, out);
}